// Round 1
// baseline (3658.924 us; speedup 1.0000x reference)
//
#include <hip/hip_runtime.h>
#include <math.h>

#define N_NODES 100000
#define N_EDGES 6400000
#define DIM     128
#define NROLES  8
#define ALPHA   0.15f
#define PR_ITERS 10

// ---------------------------------------------------------------------------
// K0: tiny fp64 solve on device: M = A^T (A A^T)^{-1}, A = H^T (4 x R).
// M is [R,4]; per-node role vector w = M @ x, x = [deg, pr, e0, e1].
// ---------------------------------------------------------------------------
__global__ void k_prep_M(const float* __restrict__ H, float* __restrict__ Mout) {
    if (threadIdx.x != 0 || blockIdx.x != 0) return;
    double G[4][4];
    for (int i = 0; i < 4; ++i)
        for (int j = 0; j < 4; ++j) {
            double s = 0.0;
            for (int r = 0; r < NROLES; ++r)
                s += (double)H[r * 4 + i] * (double)H[r * 4 + j];
            G[i][j] = s;
        }
    // Gauss-Jordan inverse with partial pivoting
    double aug[4][8];
    for (int i = 0; i < 4; ++i)
        for (int j = 0; j < 4; ++j) {
            aug[i][j] = G[i][j];
            aug[i][j + 4] = (i == j) ? 1.0 : 0.0;
        }
    for (int c = 0; c < 4; ++c) {
        int p = c; double best = fabs(aug[c][c]);
        for (int r = c + 1; r < 4; ++r) {
            double v = fabs(aug[r][c]);
            if (v > best) { best = v; p = r; }
        }
        if (p != c)
            for (int j = 0; j < 8; ++j) {
                double t = aug[c][j]; aug[c][j] = aug[p][j]; aug[p][j] = t;
            }
        double piv = aug[c][c];
        for (int j = 0; j < 8; ++j) aug[c][j] /= piv;
        for (int r = 0; r < 4; ++r) {
            if (r == c) continue;
            double f = aug[r][c];
            for (int j = 0; j < 8; ++j) aug[r][j] -= f * aug[c][j];
        }
    }
    // M[r][k] = sum_j H[r][j] * Ginv[j][k]
    for (int r = 0; r < NROLES; ++r)
        for (int k = 0; k < 4; ++k) {
            double s = 0.0;
            for (int j = 0; j < 4; ++j)
                s += (double)H[r * 4 + j] * aug[j][k + 4];
            Mout[r * 4 + k] = (float)s;
        }
}

// ---------------------------------------------------------------------------
// K1: out-degree bincount
// ---------------------------------------------------------------------------
__global__ void k_deg(const int* __restrict__ src, float* __restrict__ deg) {
    int e = blockIdx.x * blockDim.x + threadIdx.x;
    if (e < N_EDGES) atomicAdd(&deg[src[e]], 1.0f);
}

// ---------------------------------------------------------------------------
// K2: init pr0 and per-node scale s[v] = (1-alpha)/max(deg,1)
// ---------------------------------------------------------------------------
__global__ void k_init(const float* __restrict__ deg, float* __restrict__ s,
                       float* __restrict__ pr) {
    int v = blockIdx.x * blockDim.x + threadIdx.x;
    if (v < N_NODES) {
        s[v]  = (1.0f - ALPHA) / fmaxf(deg[v], 1.0f);
        pr[v] = 1.0f / (float)N_NODES;
    }
}

// ---------------------------------------------------------------------------
// K3: per-iteration: val = pr*s ; prn = alpha/N
// ---------------------------------------------------------------------------
__global__ void k_val(const float* __restrict__ pr, const float* __restrict__ s,
                      float* __restrict__ val, float* __restrict__ prn) {
    int v = blockIdx.x * blockDim.x + threadIdx.x;
    if (v < N_NODES) {
        val[v] = pr[v] * s[v];
        prn[v] = ALPHA / (float)N_NODES;
    }
}

// ---------------------------------------------------------------------------
// K4: scatter: prn[dst[e]] += val[src[e]]
// ---------------------------------------------------------------------------
__global__ void k_scatter(const int* __restrict__ src, const int* __restrict__ dst,
                          const float* __restrict__ val, float* __restrict__ prn) {
    int e = blockIdx.x * blockDim.x + threadIdx.x;
    if (e < N_EDGES) atomicAdd(&prn[dst[e]], val[src[e]]);
}

// ---------------------------------------------------------------------------
// K5: fused resizer + role solve + normalize. One 64-lane wave per output row.
// ---------------------------------------------------------------------------
__global__ void k_final(const float* __restrict__ emb, const float* __restrict__ rW,
                        const float* __restrict__ rb, const int* __restrict__ batch,
                        const float* __restrict__ deg, const float* __restrict__ pr,
                        const float* __restrict__ M, float* __restrict__ out) {
    int wid  = (blockIdx.x * blockDim.x + threadIdx.x) >> 6;  // wave id = row
    int lane = threadIdx.x & 63;
    if (wid >= N_NODES) return;

    const float* row = emb + (size_t)wid * DIM;
    float e0 = row[lane];
    float e1 = row[lane + 64];
    float2 w0 = ((const float2*)rW)[lane];        // rW[lane][0..1]
    float2 w1 = ((const float2*)rW)[lane + 64];
    float a0 = e0 * w0.x + e1 * w1.x;
    float a1 = e0 * w0.y + e1 * w1.y;
    #pragma unroll
    for (int off = 32; off; off >>= 1) {
        a0 += __shfl_xor(a0, off);
        a1 += __shfl_xor(a1, off);
    }

    int bn = batch[wid];
    float x0 = deg[bn];
    float x1 = pr[bn];
    float x2 = a0 + rb[0];
    float x3 = a1 + rb[1];

    float wr = 0.0f;
    if (lane < NROLES) {
        const float* m = M + lane * 4;
        wr = m[0] * x0 + m[1] * x1 + m[2] * x2 + m[3] * x3;
    }
    float sq = wr * wr;
    #pragma unroll
    for (int off = 4; off; off >>= 1) sq += __shfl_xor(sq, off);  // lanes 0..7 group
    float inv = 1.0f / fmaxf(sqrtf(sq), 1e-12f);
    if (lane < NROLES) out[(size_t)wid * NROLES + lane] = wr * inv;
}

// ---------------------------------------------------------------------------
extern "C" void kernel_launch(void* const* d_in, const int* in_sizes, int n_in,
                              void* d_out, int out_size, void* d_ws, size_t ws_size,
                              hipStream_t stream) {
    const int*   edge  = (const int*)d_in[0];
    const int*   src   = edge;
    const int*   dst   = edge + N_EDGES;
    const int*   batch = (const int*)d_in[1];
    const float* emb   = (const float*)d_in[2];
    const float* rW    = (const float*)d_in[3];
    const float* rb    = (const float*)d_in[4];
    const float* H     = (const float*)d_in[5];
    float*       out   = (float*)d_out;

    float* deg = (float*)d_ws;
    float* s   = deg + N_NODES;
    float* pra = s   + N_NODES;
    float* prb = pra + N_NODES;
    float* val = prb + N_NODES;
    float* M   = val + N_NODES;

    hipMemsetAsync(deg, 0, N_NODES * sizeof(float), stream);
    k_prep_M<<<1, 1, 0, stream>>>(H, M);

    const int EB = 256;
    const int EG = (N_EDGES + EB - 1) / EB;     // 25000
    const int NB = 256;
    const int NG = (N_NODES + NB - 1) / NB;     // 391

    k_deg<<<EG, EB, 0, stream>>>(src, deg);
    k_init<<<NG, NB, 0, stream>>>(deg, s, pra);

    float* cur = pra;
    float* nxt = prb;
    for (int it = 0; it < PR_ITERS; ++it) {
        k_val<<<NG, NB, 0, stream>>>(cur, s, val, nxt);
        k_scatter<<<EG, EB, 0, stream>>>(src, dst, val, nxt);
        float* t = cur; cur = nxt; nxt = t;
    }

    // final: 4 waves (rows) per 256-thread block
    const int FG = (N_NODES + 3) / 4;           // 25000
    k_final<<<FG, 256, 0, stream>>>(emb, rW, rb, batch, deg, cur, M, out);
}

// Round 2
// 887.824 us; speedup vs baseline: 4.1212x; 4.1212x over previous
//
#include <hip/hip_runtime.h>
#include <math.h>

#define N_NODES 100000
#define N_EDGES 6400000
#define DIM     128
#define NROLES  8
#define ALPHA   0.15f
#define PR_ITERS 10

#define BUCKET_SHIFT 9
#define BUCKET_SIZE  512
#define NBUCKET      196          // ceil(100000/512)
#define NBLK_BIN     256
#define CHUNK        25000        // ceil(E / NBLK_BIN)

// ---------------------------------------------------------------------------
// K0: tiny fp64 solve on device: M = A^T (A A^T)^{-1}, A = H^T (4 x R).
// ---------------------------------------------------------------------------
__global__ void k_prep_M(const float* __restrict__ H, float* __restrict__ Mout) {
    if (threadIdx.x != 0 || blockIdx.x != 0) return;
    double G[4][4];
    for (int i = 0; i < 4; ++i)
        for (int j = 0; j < 4; ++j) {
            double s = 0.0;
            for (int r = 0; r < NROLES; ++r)
                s += (double)H[r * 4 + i] * (double)H[r * 4 + j];
            G[i][j] = s;
        }
    double aug[4][8];
    for (int i = 0; i < 4; ++i)
        for (int j = 0; j < 4; ++j) {
            aug[i][j] = G[i][j];
            aug[i][j + 4] = (i == j) ? 1.0 : 0.0;
        }
    for (int c = 0; c < 4; ++c) {
        int p = c; double best = fabs(aug[c][c]);
        for (int r = c + 1; r < 4; ++r) {
            double v = fabs(aug[r][c]);
            if (v > best) { best = v; p = r; }
        }
        if (p != c)
            for (int j = 0; j < 8; ++j) {
                double t = aug[c][j]; aug[c][j] = aug[p][j]; aug[p][j] = t;
            }
        double piv = aug[c][c];
        for (int j = 0; j < 8; ++j) aug[c][j] /= piv;
        for (int r = 0; r < 4; ++r) {
            if (r == c) continue;
            double f = aug[r][c];
            for (int j = 0; j < 8; ++j) aug[r][j] -= f * aug[c][j];
        }
    }
    for (int r = 0; r < NROLES; ++r)
        for (int k = 0; k < 4; ++k) {
            double s = 0.0;
            for (int j = 0; j < 4; ++j)
                s += (double)H[r * 4 + j] * aug[j][k + 4];
            Mout[r * 4 + k] = (float)s;
        }
}

// ---------------------------------------------------------------------------
// K1: fused out-degree bincount (global atomics, the one unavoidable atomic
// pass) + per-block LDS histogram of dst-buckets.
// ---------------------------------------------------------------------------
__global__ __launch_bounds__(256)
void k_deg_hist(const int* __restrict__ src, const int* __restrict__ dst,
                float* __restrict__ deg, unsigned* __restrict__ counts) {
    __shared__ unsigned h[NBUCKET];
    for (int i = threadIdx.x; i < NBUCKET; i += 256) h[i] = 0;
    __syncthreads();
    int beg = blockIdx.x * CHUNK;
    int end = min(beg + CHUNK, N_EDGES);
    for (int e = beg + threadIdx.x; e < end; e += 256) {
        atomicAdd(&deg[src[e]], 1.0f);
        atomicAdd(&h[((unsigned)dst[e]) >> BUCKET_SHIFT], 1u);
    }
    __syncthreads();
    for (int i = threadIdx.x; i < NBUCKET; i += 256)
        counts[blockIdx.x * NBUCKET + i] = h[i];
}

// ---------------------------------------------------------------------------
// K2a: per-bucket exclusive scan over the 256 per-block counts.
// offs[blk][bucket] = sum_{b<blk} counts[b][bucket]; btot[bucket] = total.
// ---------------------------------------------------------------------------
__global__ __launch_bounds__(256)
void k_scanA(const unsigned* __restrict__ counts, unsigned* __restrict__ offs,
             unsigned* __restrict__ btot) {
    int bucket = blockIdx.x, t = threadIdx.x, lane = t & 63, wv = t >> 6;
    unsigned v = counts[t * NBUCKET + bucket], x = v;
    #pragma unroll
    for (int o = 1; o < 64; o <<= 1) {
        unsigned y = __shfl_up(x, o);
        if (lane >= o) x += y;
    }
    __shared__ unsigned wsum[4];
    if (lane == 63) wsum[wv] = x;
    __syncthreads();
    unsigned carry = 0;
    for (int w = 0; w < wv; ++w) carry += wsum[w];
    x += carry;
    offs[t * NBUCKET + bucket] = x - v;   // exclusive
    if (t == 255) btot[bucket] = x;       // inclusive total
}

// ---------------------------------------------------------------------------
// K2b: exclusive scan of the 196 bucket totals -> bucket base offsets.
// bbase[NBUCKET] = E (total), used as the end sentinel.
// ---------------------------------------------------------------------------
__global__ __launch_bounds__(256)
void k_scanB(const unsigned* __restrict__ btot, unsigned* __restrict__ bbase) {
    int t = threadIdx.x, lane = t & 63, wv = t >> 6;
    unsigned v = (t < NBUCKET) ? btot[t] : 0u, x = v;
    #pragma unroll
    for (int o = 1; o < 64; o <<= 1) {
        unsigned y = __shfl_up(x, o);
        if (lane >= o) x += y;
    }
    __shared__ unsigned wsum[4];
    if (lane == 63) wsum[wv] = x;
    __syncthreads();
    unsigned carry = 0;
    for (int w = 0; w < wv; ++w) carry += wsum[w];
    x += carry;
    if (t <= NBUCKET) bbase[t] = x - v;   // exclusive
}

// ---------------------------------------------------------------------------
// K3: placement — scatter packed records grouped by dst-bucket.
// rec = (dst_local << 17) | src   (dst_local < 512, src < 131072)
// ---------------------------------------------------------------------------
__global__ __launch_bounds__(256)
void k_place(const int* __restrict__ src, const int* __restrict__ dst,
             const unsigned* __restrict__ offs, const unsigned* __restrict__ bbase,
             unsigned* __restrict__ rec) {
    __shared__ unsigned cnt[NBUCKET];
    for (int i = threadIdx.x; i < NBUCKET; i += 256)
        cnt[i] = offs[blockIdx.x * NBUCKET + i] + bbase[i];
    __syncthreads();
    int beg = blockIdx.x * CHUNK;
    int end = min(beg + CHUNK, N_EDGES);
    for (int e = beg + threadIdx.x; e < end; e += 256) {
        unsigned d = (unsigned)dst[e];
        unsigned b = d >> BUCKET_SHIFT;
        unsigned pos = atomicAdd(&cnt[b], 1u);
        rec[pos] = ((d & (BUCKET_SIZE - 1)) << 17) | (unsigned)src[e];
    }
}

// ---------------------------------------------------------------------------
// K4: init scale and val0: s = (1-a)/max(deg,1); val0 = s * (1/N)
// ---------------------------------------------------------------------------
__global__ void k_init(const float* __restrict__ deg, float* __restrict__ s,
                       float* __restrict__ val0) {
    int v = blockIdx.x * blockDim.x + threadIdx.x;
    if (v < N_NODES) {
        float sv = (1.0f - ALPHA) / fmaxf(deg[v], 1.0f);
        s[v] = sv;
        val0[v] = sv * (1.0f / (float)N_NODES);
    }
}

// ---------------------------------------------------------------------------
// K5: one PageRank iteration, atomic-free at global scope.
// Block = one dst-bucket: LDS accumulate val[src], then write
// pr = acc + a/N and valn = pr * s for the next iteration.
// ---------------------------------------------------------------------------
__global__ __launch_bounds__(256)
void k_iter(const unsigned* __restrict__ rec, const unsigned* __restrict__ bbase,
            const float* __restrict__ val, const float* __restrict__ s,
            float* __restrict__ pr, float* __restrict__ valn) {
    __shared__ float acc[BUCKET_SIZE];
    int t = threadIdx.x;
    acc[t] = 0.0f;
    acc[t + 256] = 0.0f;
    __syncthreads();
    int b = blockIdx.x;
    unsigned st = bbase[b], en = bbase[b + 1], n = en - st;
    unsigned mainN = n & ~1023u;
    for (unsigned i = t; i < mainN; i += 1024) {
        unsigned r0 = rec[st + i];
        unsigned r1 = rec[st + i + 256];
        unsigned r2 = rec[st + i + 512];
        unsigned r3 = rec[st + i + 768];
        float v0 = val[r0 & 0x1FFFFu];
        float v1 = val[r1 & 0x1FFFFu];
        float v2 = val[r2 & 0x1FFFFu];
        float v3 = val[r3 & 0x1FFFFu];
        atomicAdd(&acc[r0 >> 17], v0);
        atomicAdd(&acc[r1 >> 17], v1);
        atomicAdd(&acc[r2 >> 17], v2);
        atomicAdd(&acc[r3 >> 17], v3);
    }
    for (unsigned i = mainN + t; i < n; i += 256) {
        unsigned r = rec[st + i];
        atomicAdd(&acc[r >> 17], val[r & 0x1FFFFu]);
    }
    __syncthreads();
    #pragma unroll
    for (int k = 0; k < 2; ++k) {
        int v = b * BUCKET_SIZE + t + k * 256;
        if (v < N_NODES) {
            float p = acc[t + k * 256] + ALPHA / (float)N_NODES;
            pr[v] = p;
            valn[v] = p * s[v];
        }
    }
}

// ---------------------------------------------------------------------------
// K6: fused resizer + role solve + normalize. One 64-lane wave per output row.
// ---------------------------------------------------------------------------
__global__ __launch_bounds__(256)
void k_final(const float* __restrict__ emb, const float* __restrict__ rW,
             const float* __restrict__ rb, const int* __restrict__ batch,
             const float* __restrict__ deg, const float* __restrict__ pr,
             const float* __restrict__ M, float* __restrict__ out) {
    int wid  = (blockIdx.x * blockDim.x + threadIdx.x) >> 6;
    int lane = threadIdx.x & 63;
    if (wid >= N_NODES) return;

    const float* row = emb + (size_t)wid * DIM;
    float e0 = row[lane];
    float e1 = row[lane + 64];
    float2 w0 = ((const float2*)rW)[lane];
    float2 w1 = ((const float2*)rW)[lane + 64];
    float a0 = e0 * w0.x + e1 * w1.x;
    float a1 = e0 * w0.y + e1 * w1.y;
    #pragma unroll
    for (int off = 32; off; off >>= 1) {
        a0 += __shfl_xor(a0, off);
        a1 += __shfl_xor(a1, off);
    }

    int bn = batch[wid];
    float x0 = deg[bn];
    float x1 = pr[bn];
    float x2 = a0 + rb[0];
    float x3 = a1 + rb[1];

    float wr = 0.0f;
    if (lane < NROLES) {
        const float* m = M + lane * 4;
        wr = m[0] * x0 + m[1] * x1 + m[2] * x2 + m[3] * x3;
    }
    float sq = wr * wr;
    #pragma unroll
    for (int off = 4; off; off >>= 1) sq += __shfl_xor(sq, off);
    float inv = 1.0f / fmaxf(sqrtf(sq), 1e-12f);
    if (lane < NROLES) out[(size_t)wid * NROLES + lane] = wr * inv;
}

// ---------------------------------------------------------------------------
extern "C" void kernel_launch(void* const* d_in, const int* in_sizes, int n_in,
                              void* d_out, int out_size, void* d_ws, size_t ws_size,
                              hipStream_t stream) {
    const int*   edge  = (const int*)d_in[0];
    const int*   src   = edge;
    const int*   dst   = edge + N_EDGES;
    const int*   batch = (const int*)d_in[1];
    const float* emb   = (const float*)d_in[2];
    const float* rW    = (const float*)d_in[3];
    const float* rb    = (const float*)d_in[4];
    const float* H     = (const float*)d_in[5];
    float*       out   = (float*)d_out;

    // workspace carve-up (all 4-byte elements)
    float*    deg    = (float*)d_ws;                 // 100000
    float*    s      = deg   + 100352;
    float*    pr     = s     + 100352;
    float*    valA   = pr    + 100352;
    float*    valB   = valA  + 100352;
    float*    M      = valB  + 100352;               // 32
    unsigned* counts = (unsigned*)(M + 32);          // 256*196
    unsigned* offs   = counts + NBLK_BIN * NBUCKET;  // 256*196
    unsigned* btot   = offs   + NBLK_BIN * NBUCKET;  // 256
    unsigned* bbase  = btot   + 256;                 // 256
    unsigned* rec    = bbase  + 256;                 // 6.4M

    hipMemsetAsync(deg, 0, N_NODES * sizeof(float), stream);
    k_prep_M<<<1, 1, 0, stream>>>(H, M);

    k_deg_hist<<<NBLK_BIN, 256, 0, stream>>>(src, dst, deg, counts);
    k_scanA<<<NBUCKET, 256, 0, stream>>>(counts, offs, btot);
    k_scanB<<<1, 256, 0, stream>>>(btot, bbase);
    k_place<<<NBLK_BIN, 256, 0, stream>>>(src, dst, offs, bbase, rec);

    const int NG = (N_NODES + 255) / 256;
    k_init<<<NG, 256, 0, stream>>>(deg, s, valA);

    float* vcur = valA;
    float* vnxt = valB;
    for (int it = 0; it < PR_ITERS; ++it) {
        k_iter<<<NBUCKET, 256, 0, stream>>>(rec, bbase, vcur, s, pr, vnxt);
        float* t = vcur; vcur = vnxt; vnxt = t;
    }

    const int FG = (N_NODES + 3) / 4;
    k_final<<<FG, 256, 0, stream>>>(emb, rW, rb, batch, deg, pr, M, out);
}

// Round 3
// 573.676 us; speedup vs baseline: 6.3780x; 1.5476x over previous
//
#include <hip/hip_runtime.h>
#include <math.h>

#define N_NODES 100000
#define N_EDGES 6400000
#define DIM     128
#define NROLES  8
#define ALPHA   0.15f
#define PR_ITERS 10

#define BUCKET_SHIFT 9
#define BUCKET_SIZE  512
#define NBUCKET      196          // ceil(100000/512)
#define NB2          392          // dst buckets [0,196) + src buckets [196,392)
#define NBLK_BIN     256
#define CHUNK        25000        // E / NBLK_BIN exactly

// ---------------------------------------------------------------------------
// K0: tiny fp64 solve on device: M = A^T (A A^T)^{-1}, A = H^T (4 x R).
// ---------------------------------------------------------------------------
__global__ void k_prep_M(const float* __restrict__ H, float* __restrict__ Mout) {
    if (threadIdx.x != 0 || blockIdx.x != 0) return;
    double G[4][4];
    for (int i = 0; i < 4; ++i)
        for (int j = 0; j < 4; ++j) {
            double s = 0.0;
            for (int r = 0; r < NROLES; ++r)
                s += (double)H[r * 4 + i] * (double)H[r * 4 + j];
            G[i][j] = s;
        }
    double aug[4][8];
    for (int i = 0; i < 4; ++i)
        for (int j = 0; j < 4; ++j) {
            aug[i][j] = G[i][j];
            aug[i][j + 4] = (i == j) ? 1.0 : 0.0;
        }
    for (int c = 0; c < 4; ++c) {
        int p = c; double best = fabs(aug[c][c]);
        for (int r = c + 1; r < 4; ++r) {
            double v = fabs(aug[r][c]);
            if (v > best) { best = v; p = r; }
        }
        if (p != c)
            for (int j = 0; j < 8; ++j) {
                double t = aug[c][j]; aug[c][j] = aug[p][j]; aug[p][j] = t;
            }
        double piv = aug[c][c];
        for (int j = 0; j < 8; ++j) aug[c][j] /= piv;
        for (int r = 0; r < 4; ++r) {
            if (r == c) continue;
            double f = aug[r][c];
            for (int j = 0; j < 8; ++j) aug[r][j] -= f * aug[c][j];
        }
    }
    for (int r = 0; r < NROLES; ++r)
        for (int k = 0; k < 4; ++k) {
            double s = 0.0;
            for (int j = 0; j < 4; ++j)
                s += (double)H[r * 4 + j] * aug[j][k + 4];
            Mout[r * 4 + k] = (float)s;
        }
}

// ---------------------------------------------------------------------------
// K1: per-block LDS histograms over BOTH dst-buckets and src-buckets.
// Zero global atomics.
// ---------------------------------------------------------------------------
__global__ __launch_bounds__(256)
void k_hist(const int* __restrict__ src, const int* __restrict__ dst,
            unsigned* __restrict__ counts) {
    __shared__ unsigned h[NB2];
    for (int i = threadIdx.x; i < NB2; i += 256) h[i] = 0;
    __syncthreads();
    int beg = blockIdx.x * CHUNK;
    int t = threadIdx.x;
    // main: int4 (CHUNK = 24*1024 + 424)
    int mainEnd = beg + 24576;
    for (int e = beg + t * 4; e < mainEnd; e += 1024) {
        int4 s4 = *(const int4*)(src + e);
        int4 d4 = *(const int4*)(dst + e);
        atomicAdd(&h[((unsigned)d4.x) >> BUCKET_SHIFT], 1u);
        atomicAdd(&h[((unsigned)d4.y) >> BUCKET_SHIFT], 1u);
        atomicAdd(&h[((unsigned)d4.z) >> BUCKET_SHIFT], 1u);
        atomicAdd(&h[((unsigned)d4.w) >> BUCKET_SHIFT], 1u);
        atomicAdd(&h[NBUCKET + (((unsigned)s4.x) >> BUCKET_SHIFT)], 1u);
        atomicAdd(&h[NBUCKET + (((unsigned)s4.y) >> BUCKET_SHIFT)], 1u);
        atomicAdd(&h[NBUCKET + (((unsigned)s4.z) >> BUCKET_SHIFT)], 1u);
        atomicAdd(&h[NBUCKET + (((unsigned)s4.w) >> BUCKET_SHIFT)], 1u);
    }
    for (int e = mainEnd + t; e < beg + CHUNK; e += 256) {
        atomicAdd(&h[((unsigned)dst[e]) >> BUCKET_SHIFT], 1u);
        atomicAdd(&h[NBUCKET + (((unsigned)src[e]) >> BUCKET_SHIFT)], 1u);
    }
    __syncthreads();
    for (int i = threadIdx.x; i < NB2; i += 256)
        counts[blockIdx.x * NB2 + i] = h[i];
}

// ---------------------------------------------------------------------------
// K2a: per-bucket exclusive scan over the 256 per-block counts.
// ---------------------------------------------------------------------------
__global__ __launch_bounds__(256)
void k_scanA(const unsigned* __restrict__ counts, unsigned* __restrict__ offs,
             unsigned* __restrict__ btot) {
    int bucket = blockIdx.x, t = threadIdx.x, lane = t & 63, wv = t >> 6;
    unsigned v = counts[t * NB2 + bucket], x = v;
    #pragma unroll
    for (int o = 1; o < 64; o <<= 1) {
        unsigned y = __shfl_up(x, o);
        if (lane >= o) x += y;
    }
    __shared__ unsigned wsum[4];
    if (lane == 63) wsum[wv] = x;
    __syncthreads();
    unsigned carry = 0;
    for (int w = 0; w < wv; ++w) carry += wsum[w];
    x += carry;
    offs[t * NB2 + bucket] = x - v;       // exclusive
    if (t == 255) btot[bucket] = x;       // inclusive total
}

// ---------------------------------------------------------------------------
// K2b: exclusive scan of 196 bucket totals for each half (dst, src).
// bases[half][0..196]; entry 196 == E sentinel.
// ---------------------------------------------------------------------------
__global__ __launch_bounds__(256)
void k_scanB(const unsigned* __restrict__ btot, unsigned* __restrict__ bases) {
    int half = blockIdx.x;
    int t = threadIdx.x, lane = t & 63, wv = t >> 6;
    unsigned v = (t < NBUCKET) ? btot[half * NBUCKET + t] : 0u, x = v;
    #pragma unroll
    for (int o = 1; o < 64; o <<= 1) {
        unsigned y = __shfl_up(x, o);
        if (lane >= o) x += y;
    }
    __shared__ unsigned wsum[4];
    if (lane == 63) wsum[wv] = x;
    __syncthreads();
    unsigned carry = 0;
    for (int w = 0; w < wv; ++w) carry += wsum[w];
    x += carry;
    if (t <= NBUCKET) bases[half * 256 + t] = x - v;   // exclusive
}

// ---------------------------------------------------------------------------
// K3: placement — two record streams:
//   rec  (u32, grouped by dst-bucket): (dst_local << 17) | src
//   recs (u16, grouped by src-bucket): src_local          (for degree count)
// ---------------------------------------------------------------------------
__global__ __launch_bounds__(256)
void k_place(const int* __restrict__ src, const int* __restrict__ dst,
             const unsigned* __restrict__ offs, const unsigned* __restrict__ bases,
             unsigned* __restrict__ rec, unsigned short* __restrict__ recs) {
    __shared__ unsigned cD[NBUCKET];
    __shared__ unsigned cS[NBUCKET];
    for (int i = threadIdx.x; i < NBUCKET; i += 256) {
        cD[i] = bases[i]       + offs[blockIdx.x * NB2 + i];
        cS[i] = bases[256 + i] + offs[blockIdx.x * NB2 + NBUCKET + i];
    }
    __syncthreads();
    int beg = blockIdx.x * CHUNK;
    int t = threadIdx.x;
    int mainEnd = beg + 24576;
    for (int e = beg + t * 4; e < mainEnd; e += 1024) {
        int4 s4 = *(const int4*)(src + e);
        int4 d4 = *(const int4*)(dst + e);
        #pragma unroll
        for (int k = 0; k < 4; ++k) {
            unsigned s = (unsigned)((&s4.x)[k]);
            unsigned d = (unsigned)((&d4.x)[k]);
            unsigned pos = atomicAdd(&cD[d >> BUCKET_SHIFT], 1u);
            rec[pos] = ((d & (BUCKET_SIZE - 1)) << 17) | s;
            unsigned pos2 = atomicAdd(&cS[s >> BUCKET_SHIFT], 1u);
            recs[pos2] = (unsigned short)(s & (BUCKET_SIZE - 1));
        }
    }
    for (int e = mainEnd + t; e < beg + CHUNK; e += 256) {
        unsigned s = (unsigned)src[e];
        unsigned d = (unsigned)dst[e];
        unsigned pos = atomicAdd(&cD[d >> BUCKET_SHIFT], 1u);
        rec[pos] = ((d & (BUCKET_SIZE - 1)) << 17) | s;
        unsigned pos2 = atomicAdd(&cS[s >> BUCKET_SHIFT], 1u);
        recs[pos2] = (unsigned short)(s & (BUCKET_SIZE - 1));
    }
}

// ---------------------------------------------------------------------------
// K4: per-src-bucket degree count (LDS u32) + fused init of s and val0.
// ---------------------------------------------------------------------------
__global__ __launch_bounds__(256)
void k_count_init(const unsigned short* __restrict__ recs,
                  const unsigned* __restrict__ bases,
                  float* __restrict__ deg, float* __restrict__ s,
                  float* __restrict__ val0) {
    __shared__ unsigned cnt[BUCKET_SIZE];
    int t = threadIdx.x;
    cnt[t] = 0; cnt[t + 256] = 0;
    __syncthreads();
    int b = blockIdx.x;
    unsigned st = bases[256 + b], en = bases[256 + b + 1];
    // scalar until 8-aligned, then uint4 = 8 records
    unsigned a = (st + 7u) & ~7u;
    if (a > en) a = en;
    for (unsigned i = st + t; i < a; i += 256)
        atomicAdd(&cnt[recs[i]], 1u);
    unsigned mainN = (en - a) & ~2047u;   // 256 threads * 8 recs
    const uint4* rp = (const uint4*)(recs + a);
    for (unsigned i = t; i * 8u < mainN; i += 256) {
        uint4 r = rp[i];
        atomicAdd(&cnt[r.x & 0xFFFFu], 1u); atomicAdd(&cnt[r.x >> 16], 1u);
        atomicAdd(&cnt[r.y & 0xFFFFu], 1u); atomicAdd(&cnt[r.y >> 16], 1u);
        atomicAdd(&cnt[r.z & 0xFFFFu], 1u); atomicAdd(&cnt[r.z >> 16], 1u);
        atomicAdd(&cnt[r.w & 0xFFFFu], 1u); atomicAdd(&cnt[r.w >> 16], 1u);
    }
    for (unsigned i = a + mainN + t; i < en; i += 256)
        atomicAdd(&cnt[recs[i]], 1u);
    __syncthreads();
    #pragma unroll
    for (int k = 0; k < 2; ++k) {
        int v = b * BUCKET_SIZE + t + k * 256;
        if (v < N_NODES) {
            float d = (float)cnt[t + k * 256];
            float sv = (1.0f - ALPHA) / fmaxf(d, 1.0f);
            deg[v] = d;
            s[v] = sv;
            val0[v] = sv * (1.0f / (float)N_NODES);
        }
    }
}

// ---------------------------------------------------------------------------
// K5: one PageRank iteration, atomic-free at global scope.
// ---------------------------------------------------------------------------
__global__ __launch_bounds__(256)
void k_iter(const unsigned* __restrict__ rec, const unsigned* __restrict__ bases,
            const float* __restrict__ val, const float* __restrict__ s,
            float* __restrict__ pr, float* __restrict__ valn) {
    __shared__ float acc[BUCKET_SIZE];
    int t = threadIdx.x;
    acc[t] = 0.0f;
    acc[t + 256] = 0.0f;
    __syncthreads();
    int b = blockIdx.x;
    unsigned st = bases[b], en = bases[b + 1], n = en - st;
    unsigned mainN = n & ~1023u;
    for (unsigned i = t; i < mainN; i += 1024) {
        unsigned r0 = rec[st + i];
        unsigned r1 = rec[st + i + 256];
        unsigned r2 = rec[st + i + 512];
        unsigned r3 = rec[st + i + 768];
        float v0 = val[r0 & 0x1FFFFu];
        float v1 = val[r1 & 0x1FFFFu];
        float v2 = val[r2 & 0x1FFFFu];
        float v3 = val[r3 & 0x1FFFFu];
        atomicAdd(&acc[r0 >> 17], v0);
        atomicAdd(&acc[r1 >> 17], v1);
        atomicAdd(&acc[r2 >> 17], v2);
        atomicAdd(&acc[r3 >> 17], v3);
    }
    for (unsigned i = mainN + t; i < n; i += 256) {
        unsigned r = rec[st + i];
        atomicAdd(&acc[r >> 17], val[r & 0x1FFFFu]);
    }
    __syncthreads();
    #pragma unroll
    for (int k = 0; k < 2; ++k) {
        int v = b * BUCKET_SIZE + t + k * 256;
        if (v < N_NODES) {
            float p = acc[t + k * 256] + ALPHA / (float)N_NODES;
            pr[v] = p;
            valn[v] = p * s[v];
        }
    }
}

// ---------------------------------------------------------------------------
// K6: fused resizer + role solve + normalize. One 64-lane wave per output row.
// ---------------------------------------------------------------------------
__global__ __launch_bounds__(256)
void k_final(const float* __restrict__ emb, const float* __restrict__ rW,
             const float* __restrict__ rb, const int* __restrict__ batch,
             const float* __restrict__ deg, const float* __restrict__ pr,
             const float* __restrict__ M, float* __restrict__ out) {
    int wid  = (blockIdx.x * blockDim.x + threadIdx.x) >> 6;
    int lane = threadIdx.x & 63;
    if (wid >= N_NODES) return;

    const float* row = emb + (size_t)wid * DIM;
    float e0 = row[lane];
    float e1 = row[lane + 64];
    float2 w0 = ((const float2*)rW)[lane];
    float2 w1 = ((const float2*)rW)[lane + 64];
    float a0 = e0 * w0.x + e1 * w1.x;
    float a1 = e0 * w0.y + e1 * w1.y;
    #pragma unroll
    for (int off = 32; off; off >>= 1) {
        a0 += __shfl_xor(a0, off);
        a1 += __shfl_xor(a1, off);
    }

    int bn = batch[wid];
    float x0 = deg[bn];
    float x1 = pr[bn];
    float x2 = a0 + rb[0];
    float x3 = a1 + rb[1];

    float wr = 0.0f;
    if (lane < NROLES) {
        const float* m = M + lane * 4;
        wr = m[0] * x0 + m[1] * x1 + m[2] * x2 + m[3] * x3;
    }
    float sq = wr * wr;
    #pragma unroll
    for (int off = 4; off; off >>= 1) sq += __shfl_xor(sq, off);
    float inv = 1.0f / fmaxf(sqrtf(sq), 1e-12f);
    if (lane < NROLES) out[(size_t)wid * NROLES + lane] = wr * inv;
}

// ---------------------------------------------------------------------------
extern "C" void kernel_launch(void* const* d_in, const int* in_sizes, int n_in,
                              void* d_out, int out_size, void* d_ws, size_t ws_size,
                              hipStream_t stream) {
    const int*   edge  = (const int*)d_in[0];
    const int*   src   = edge;
    const int*   dst   = edge + N_EDGES;
    const int*   batch = (const int*)d_in[1];
    const float* emb   = (const float*)d_in[2];
    const float* rW    = (const float*)d_in[3];
    const float* rb    = (const float*)d_in[4];
    const float* H     = (const float*)d_in[5];
    float*       out   = (float*)d_out;

    // workspace carve-up (u32 words)
    float*    deg    = (float*)d_ws;                 // 100352
    float*    s      = deg   + 100352;
    float*    pr     = s     + 100352;
    float*    valA   = pr    + 100352;
    float*    valB   = valA  + 100352;
    float*    M      = valB  + 100352;               // 32
    unsigned* counts = (unsigned*)(M + 32);          // 256*392
    unsigned* offs   = counts + NBLK_BIN * NB2;      // 256*392
    unsigned* btot   = offs   + NBLK_BIN * NB2;      // 512
    unsigned* bases  = btot   + 512;                 // 512 (dst@0, src@256)
    unsigned* rec    = bases  + 512;                 // 6.4M u32
    unsigned short* recs = (unsigned short*)(rec + N_EDGES);  // 6.4M u16

    k_prep_M<<<1, 1, 0, stream>>>(H, M);

    k_hist <<<NBLK_BIN, 256, 0, stream>>>(src, dst, counts);
    k_scanA<<<NB2,      256, 0, stream>>>(counts, offs, btot);
    k_scanB<<<2,        256, 0, stream>>>(btot, bases);
    k_place<<<NBLK_BIN, 256, 0, stream>>>(src, dst, offs, bases, rec, recs);
    k_count_init<<<NBUCKET, 256, 0, stream>>>(recs, bases, deg, s, valA);

    float* vcur = valA;
    float* vnxt = valB;
    for (int it = 0; it < PR_ITERS; ++it) {
        k_iter<<<NBUCKET, 256, 0, stream>>>(rec, bases, vcur, s, pr, vnxt);
        float* t = vcur; vcur = vnxt; vnxt = t;
    }

    const int FG = (N_NODES + 3) / 4;
    k_final<<<FG, 256, 0, stream>>>(emb, rW, rb, batch, deg, pr, M, out);
}

// Round 4
// 541.628 us; speedup vs baseline: 6.7554x; 1.0592x over previous
//
#include <hip/hip_runtime.h>
#include <math.h>

#define N_NODES 100000
#define N_EDGES 6400000
#define DIM     128
#define NROLES  8
#define ALPHA   0.15f
#define PR_ITERS 10

#define BUCKET_SHIFT 9
#define BUCKET_SIZE  512
#define NBUCKET      196          // ceil(100000/512)
#define NB2          392          // dst buckets [0,196) + src buckets [196,392)
#define NBLK_BIN     256
#define CHUNK        25000        // E / NBLK_BIN exactly
#define SEG          8            // segments per bucket in the iteration

// ---------------------------------------------------------------------------
// K0: tiny fp64 solve on device: M = A^T (A A^T)^{-1}, A = H^T (4 x R).
// ---------------------------------------------------------------------------
__global__ void k_prep_M(const float* __restrict__ H, float* __restrict__ Mout) {
    if (threadIdx.x != 0 || blockIdx.x != 0) return;
    double G[4][4];
    for (int i = 0; i < 4; ++i)
        for (int j = 0; j < 4; ++j) {
            double s = 0.0;
            for (int r = 0; r < NROLES; ++r)
                s += (double)H[r * 4 + i] * (double)H[r * 4 + j];
            G[i][j] = s;
        }
    double aug[4][8];
    for (int i = 0; i < 4; ++i)
        for (int j = 0; j < 4; ++j) {
            aug[i][j] = G[i][j];
            aug[i][j + 4] = (i == j) ? 1.0 : 0.0;
        }
    for (int c = 0; c < 4; ++c) {
        int p = c; double best = fabs(aug[c][c]);
        for (int r = c + 1; r < 4; ++r) {
            double v = fabs(aug[r][c]);
            if (v > best) { best = v; p = r; }
        }
        if (p != c)
            for (int j = 0; j < 8; ++j) {
                double t = aug[c][j]; aug[c][j] = aug[p][j]; aug[p][j] = t;
            }
        double piv = aug[c][c];
        for (int j = 0; j < 8; ++j) aug[c][j] /= piv;
        for (int r = 0; r < 4; ++r) {
            if (r == c) continue;
            double f = aug[r][c];
            for (int j = 0; j < 8; ++j) aug[r][j] -= f * aug[c][j];
        }
    }
    for (int r = 0; r < NROLES; ++r)
        for (int k = 0; k < 4; ++k) {
            double s = 0.0;
            for (int j = 0; j < 4; ++j)
                s += (double)H[r * 4 + j] * aug[j][k + 4];
            Mout[r * 4 + k] = (float)s;
        }
}

// ---------------------------------------------------------------------------
// K1: per-block LDS histograms over BOTH dst-buckets and src-buckets.
// ---------------------------------------------------------------------------
__global__ __launch_bounds__(256)
void k_hist(const int* __restrict__ src, const int* __restrict__ dst,
            unsigned* __restrict__ counts) {
    __shared__ unsigned h[NB2];
    for (int i = threadIdx.x; i < NB2; i += 256) h[i] = 0;
    __syncthreads();
    int beg = blockIdx.x * CHUNK;
    int t = threadIdx.x;
    int mainEnd = beg + 24576;
    for (int e = beg + t * 4; e < mainEnd; e += 1024) {
        int4 s4 = *(const int4*)(src + e);
        int4 d4 = *(const int4*)(dst + e);
        atomicAdd(&h[((unsigned)d4.x) >> BUCKET_SHIFT], 1u);
        atomicAdd(&h[((unsigned)d4.y) >> BUCKET_SHIFT], 1u);
        atomicAdd(&h[((unsigned)d4.z) >> BUCKET_SHIFT], 1u);
        atomicAdd(&h[((unsigned)d4.w) >> BUCKET_SHIFT], 1u);
        atomicAdd(&h[NBUCKET + (((unsigned)s4.x) >> BUCKET_SHIFT)], 1u);
        atomicAdd(&h[NBUCKET + (((unsigned)s4.y) >> BUCKET_SHIFT)], 1u);
        atomicAdd(&h[NBUCKET + (((unsigned)s4.z) >> BUCKET_SHIFT)], 1u);
        atomicAdd(&h[NBUCKET + (((unsigned)s4.w) >> BUCKET_SHIFT)], 1u);
    }
    for (int e = mainEnd + t; e < beg + CHUNK; e += 256) {
        atomicAdd(&h[((unsigned)dst[e]) >> BUCKET_SHIFT], 1u);
        atomicAdd(&h[NBUCKET + (((unsigned)src[e]) >> BUCKET_SHIFT)], 1u);
    }
    __syncthreads();
    for (int i = threadIdx.x; i < NB2; i += 256)
        counts[blockIdx.x * NB2 + i] = h[i];
}

// ---------------------------------------------------------------------------
// K2a: per-bucket exclusive scan over the 256 per-block counts.
// ---------------------------------------------------------------------------
__global__ __launch_bounds__(256)
void k_scanA(const unsigned* __restrict__ counts, unsigned* __restrict__ offs,
             unsigned* __restrict__ btot) {
    int bucket = blockIdx.x, t = threadIdx.x, lane = t & 63, wv = t >> 6;
    unsigned v = counts[t * NB2 + bucket], x = v;
    #pragma unroll
    for (int o = 1; o < 64; o <<= 1) {
        unsigned y = __shfl_up(x, o);
        if (lane >= o) x += y;
    }
    __shared__ unsigned wsum[4];
    if (lane == 63) wsum[wv] = x;
    __syncthreads();
    unsigned carry = 0;
    for (int w = 0; w < wv; ++w) carry += wsum[w];
    x += carry;
    offs[t * NB2 + bucket] = x - v;       // exclusive
    if (t == 255) btot[bucket] = x;       // inclusive total
}

// ---------------------------------------------------------------------------
// K2b: exclusive scan of 196 bucket totals for each half (dst, src).
// ---------------------------------------------------------------------------
__global__ __launch_bounds__(256)
void k_scanB(const unsigned* __restrict__ btot, unsigned* __restrict__ bases) {
    int half = blockIdx.x;
    int t = threadIdx.x, lane = t & 63, wv = t >> 6;
    unsigned v = (t < NBUCKET) ? btot[half * NBUCKET + t] : 0u, x = v;
    #pragma unroll
    for (int o = 1; o < 64; o <<= 1) {
        unsigned y = __shfl_up(x, o);
        if (lane >= o) x += y;
    }
    __shared__ unsigned wsum[4];
    if (lane == 63) wsum[wv] = x;
    __syncthreads();
    unsigned carry = 0;
    for (int w = 0; w < wv; ++w) carry += wsum[w];
    x += carry;
    if (t <= NBUCKET) bases[half * 256 + t] = x - v;   // exclusive
}

// ---------------------------------------------------------------------------
// K3: placement — two record streams:
//   rec  (u32, grouped by dst-bucket): (dst_local << 17) | src
//   recs (u16, grouped by src-bucket): src_local          (for degree count)
// ---------------------------------------------------------------------------
__global__ __launch_bounds__(256)
void k_place(const int* __restrict__ src, const int* __restrict__ dst,
             const unsigned* __restrict__ offs, const unsigned* __restrict__ bases,
             unsigned* __restrict__ rec, unsigned short* __restrict__ recs) {
    __shared__ unsigned cD[NBUCKET];
    __shared__ unsigned cS[NBUCKET];
    for (int i = threadIdx.x; i < NBUCKET; i += 256) {
        cD[i] = bases[i]       + offs[blockIdx.x * NB2 + i];
        cS[i] = bases[256 + i] + offs[blockIdx.x * NB2 + NBUCKET + i];
    }
    __syncthreads();
    int beg = blockIdx.x * CHUNK;
    int t = threadIdx.x;
    int mainEnd = beg + 24576;
    for (int e = beg + t * 4; e < mainEnd; e += 1024) {
        int4 s4 = *(const int4*)(src + e);
        int4 d4 = *(const int4*)(dst + e);
        #pragma unroll
        for (int k = 0; k < 4; ++k) {
            unsigned s = (unsigned)((&s4.x)[k]);
            unsigned d = (unsigned)((&d4.x)[k]);
            unsigned pos = atomicAdd(&cD[d >> BUCKET_SHIFT], 1u);
            rec[pos] = ((d & (BUCKET_SIZE - 1)) << 17) | s;
            unsigned pos2 = atomicAdd(&cS[s >> BUCKET_SHIFT], 1u);
            recs[pos2] = (unsigned short)(s & (BUCKET_SIZE - 1));
        }
    }
    for (int e = mainEnd + t; e < beg + CHUNK; e += 256) {
        unsigned s = (unsigned)src[e];
        unsigned d = (unsigned)dst[e];
        unsigned pos = atomicAdd(&cD[d >> BUCKET_SHIFT], 1u);
        rec[pos] = ((d & (BUCKET_SIZE - 1)) << 17) | s;
        unsigned pos2 = atomicAdd(&cS[s >> BUCKET_SHIFT], 1u);
        recs[pos2] = (unsigned short)(s & (BUCKET_SIZE - 1));
    }
}

// ---------------------------------------------------------------------------
// K4: per-src-bucket degree count (LDS u32) + fused init of s and val0.
// ---------------------------------------------------------------------------
__global__ __launch_bounds__(256)
void k_count_init(const unsigned short* __restrict__ recs,
                  const unsigned* __restrict__ bases,
                  float* __restrict__ deg, float* __restrict__ s,
                  float* __restrict__ val0) {
    __shared__ unsigned cnt[BUCKET_SIZE];
    int t = threadIdx.x;
    cnt[t] = 0; cnt[t + 256] = 0;
    __syncthreads();
    int b = blockIdx.x;
    unsigned st = bases[256 + b], en = bases[256 + b + 1];
    unsigned a = (st + 7u) & ~7u;
    if (a > en) a = en;
    for (unsigned i = st + t; i < a; i += 256)
        atomicAdd(&cnt[recs[i]], 1u);
    unsigned mainN = (en - a) & ~2047u;
    const uint4* rp = (const uint4*)(recs + a);
    for (unsigned i = t; i * 8u < mainN; i += 256) {
        uint4 r = rp[i];
        atomicAdd(&cnt[r.x & 0xFFFFu], 1u); atomicAdd(&cnt[r.x >> 16], 1u);
        atomicAdd(&cnt[r.y & 0xFFFFu], 1u); atomicAdd(&cnt[r.y >> 16], 1u);
        atomicAdd(&cnt[r.z & 0xFFFFu], 1u); atomicAdd(&cnt[r.z >> 16], 1u);
        atomicAdd(&cnt[r.w & 0xFFFFu], 1u); atomicAdd(&cnt[r.w >> 16], 1u);
    }
    for (unsigned i = a + mainN + t; i < en; i += 256)
        atomicAdd(&cnt[recs[i]], 1u);
    __syncthreads();
    #pragma unroll
    for (int k = 0; k < 2; ++k) {
        int v = b * BUCKET_SIZE + t + k * 256;
        if (v < N_NODES) {
            float d = (float)cnt[t + k * 256];
            float sv = (1.0f - ALPHA) / fmaxf(d, 1.0f);
            deg[v] = d;
            s[v] = sv;
            val0[v] = sv * (1.0f / (float)N_NODES);
        }
    }
}

// ---------------------------------------------------------------------------
// K5: segmented PageRank accumulate: block = (bucket, segment).
// Each block sums its slice of the bucket's records into LDS acc[512],
// then writes the partial coalesced. Zero global atomics.
// ---------------------------------------------------------------------------
__global__ __launch_bounds__(256)
void k_iter2(const unsigned* __restrict__ rec, const unsigned* __restrict__ bases,
             const float* __restrict__ val, float* __restrict__ partial) {
    __shared__ float acc[BUCKET_SIZE];
    int t = threadIdx.x;
    acc[t] = 0.0f;
    acc[t + 256] = 0.0f;
    __syncthreads();
    int b   = blockIdx.x >> 3;       // SEG = 8
    int seg = blockIdx.x & 7;
    unsigned st = bases[b], en = bases[b + 1], n = en - st;
    unsigned s0 = st + (unsigned)(((unsigned long long)n * (unsigned)seg) >> 3);
    unsigned s1 = st + (unsigned)(((unsigned long long)n * (unsigned)(seg + 1)) >> 3);
    unsigned a0 = (s0 + 3u) & ~3u;
    if (a0 > s1) a0 = s1;
    for (unsigned i = s0 + t; i < a0; i += 256) {
        unsigned r = rec[i];
        atomicAdd(&acc[r >> 17], val[r & 0x1FFFFu]);
    }
    unsigned nv = (s1 - a0) >> 2;
    const uint4* rp = (const uint4*)(rec + a0);
    for (unsigned i = t; i < nv; i += 256) {
        uint4 r = rp[i];
        float v0 = val[r.x & 0x1FFFFu];
        float v1 = val[r.y & 0x1FFFFu];
        float v2 = val[r.z & 0x1FFFFu];
        float v3 = val[r.w & 0x1FFFFu];
        atomicAdd(&acc[r.x >> 17], v0);
        atomicAdd(&acc[r.y >> 17], v1);
        atomicAdd(&acc[r.z >> 17], v2);
        atomicAdd(&acc[r.w >> 17], v3);
    }
    for (unsigned i = a0 + nv * 4u + t; i < s1; i += 256) {
        unsigned r = rec[i];
        atomicAdd(&acc[r >> 17], val[r & 0x1FFFFu]);
    }
    __syncthreads();
    float* p = partial + ((unsigned)blockIdx.x << 9);
    p[t] = acc[t];
    p[t + 256] = acc[t + 256];
}

// ---------------------------------------------------------------------------
// K5b: reduce 8 partials per node -> pr, valn.
// ---------------------------------------------------------------------------
__global__ __launch_bounds__(256)
void k_reduce(const float* __restrict__ partial, const float* __restrict__ s,
              float* __restrict__ pr, float* __restrict__ valn) {
    int v = blockIdx.x * 256 + threadIdx.x;
    if (v >= N_NODES) return;
    int b = v >> BUCKET_SHIFT, local = v & (BUCKET_SIZE - 1);
    const float* p = partial + ((unsigned)(b * SEG) << 9) + local;
    float sum = 0.0f;
    #pragma unroll
    for (int k = 0; k < SEG; ++k) sum += p[k << 9];
    float pv = sum + ALPHA / (float)N_NODES;
    pr[v] = pv;
    valn[v] = pv * s[v];
}

// ---------------------------------------------------------------------------
// K6: fused resizer + role solve + normalize. One 64-lane wave per output row.
// ---------------------------------------------------------------------------
__global__ __launch_bounds__(256)
void k_final(const float* __restrict__ emb, const float* __restrict__ rW,
             const float* __restrict__ rb, const int* __restrict__ batch,
             const float* __restrict__ deg, const float* __restrict__ pr,
             const float* __restrict__ M, float* __restrict__ out) {
    int wid  = (blockIdx.x * blockDim.x + threadIdx.x) >> 6;
    int lane = threadIdx.x & 63;
    if (wid >= N_NODES) return;

    const float* row = emb + (size_t)wid * DIM;
    float e0 = row[lane];
    float e1 = row[lane + 64];
    float2 w0 = ((const float2*)rW)[lane];
    float2 w1 = ((const float2*)rW)[lane + 64];
    float a0 = e0 * w0.x + e1 * w1.x;
    float a1 = e0 * w0.y + e1 * w1.y;
    #pragma unroll
    for (int off = 32; off; off >>= 1) {
        a0 += __shfl_xor(a0, off);
        a1 += __shfl_xor(a1, off);
    }

    int bn = batch[wid];
    float x0 = deg[bn];
    float x1 = pr[bn];
    float x2 = a0 + rb[0];
    float x3 = a1 + rb[1];

    float wr = 0.0f;
    if (lane < NROLES) {
        const float* m = M + lane * 4;
        wr = m[0] * x0 + m[1] * x1 + m[2] * x2 + m[3] * x3;
    }
    float sq = wr * wr;
    #pragma unroll
    for (int off = 4; off; off >>= 1) sq += __shfl_xor(sq, off);
    float inv = 1.0f / fmaxf(sqrtf(sq), 1e-12f);
    if (lane < NROLES) out[(size_t)wid * NROLES + lane] = wr * inv;
}

// ---------------------------------------------------------------------------
extern "C" void kernel_launch(void* const* d_in, const int* in_sizes, int n_in,
                              void* d_out, int out_size, void* d_ws, size_t ws_size,
                              hipStream_t stream) {
    const int*   edge  = (const int*)d_in[0];
    const int*   src   = edge;
    const int*   dst   = edge + N_EDGES;
    const int*   batch = (const int*)d_in[1];
    const float* emb   = (const float*)d_in[2];
    const float* rW    = (const float*)d_in[3];
    const float* rb    = (const float*)d_in[4];
    const float* H     = (const float*)d_in[5];
    float*       out   = (float*)d_out;

    // workspace carve-up (u32 words)
    float*    deg    = (float*)d_ws;                 // 100352
    float*    s      = deg   + 100352;
    float*    pr     = s     + 100352;
    float*    valA   = pr    + 100352;
    float*    valB   = valA  + 100352;
    float*    M      = valB  + 100352;               // 32
    unsigned* counts = (unsigned*)(M + 32);          // 256*392
    unsigned* offs   = counts + NBLK_BIN * NB2;      // 256*392
    unsigned* btot   = offs   + NBLK_BIN * NB2;      // 512
    unsigned* bases  = btot   + 512;                 // 512 (dst@0, src@256)
    unsigned* rec    = bases  + 512;                 // 6.4M u32
    unsigned short* recs = (unsigned short*)(rec + N_EDGES);  // 6.4M u16
    float*    partial = (float*)(recs + N_EDGES);    // 196*8*512 = 802816 f32

    k_prep_M<<<1, 1, 0, stream>>>(H, M);

    k_hist <<<NBLK_BIN, 256, 0, stream>>>(src, dst, counts);
    k_scanA<<<NB2,      256, 0, stream>>>(counts, offs, btot);
    k_scanB<<<2,        256, 0, stream>>>(btot, bases);
    k_place<<<NBLK_BIN, 256, 0, stream>>>(src, dst, offs, bases, rec, recs);
    k_count_init<<<NBUCKET, 256, 0, stream>>>(recs, bases, deg, s, valA);

    float* vcur = valA;
    float* vnxt = valB;
    for (int it = 0; it < PR_ITERS; ++it) {
        k_iter2 <<<NBUCKET * SEG, 256, 0, stream>>>(rec, bases, vcur, partial);
        k_reduce<<<(N_NODES + 255) / 256, 256, 0, stream>>>(partial, s, pr, vnxt);
        float* t = vcur; vcur = vnxt; vnxt = t;
    }

    const int FG = (N_NODES + 3) / 4;
    k_final<<<FG, 256, 0, stream>>>(emb, rW, rb, batch, deg, pr, M, out);
}